// Round 1
// baseline (1022.081 us; speedup 1.0000x reference)
//
#include <hip/hip_runtime.h>

#define T_STEPS 512
#define BATCH   2048
#define IN0     32
#define H       64
#define G       256      // 4*H gates
#define BR      8        // batch rows per block (rows 8..15 of MFMA tile are zero padding)
#define NTHREADS 512
#define GSTRIDE 260      // padded row stride for gates LDS (breaks bank conflicts)

typedef _Float16 half8 __attribute__((ext_vector_type(8)));
typedef float    f32x4 __attribute__((ext_vector_type(4)));

// Swizzled index into A buffers ([16 rows][128 k] fp16). Row stride is 256 B ->
// XOR row bits into the 16B-slot bits so ds_read_b128 across rows is conflict-free.
__device__ __forceinline__ int aidx(int m, int k) { return m * 128 + (k ^ (m << 3)); }

__device__ __forceinline__ float sigm(float x)   { return 1.0f / (1.0f + __expf(-x)); }
__device__ __forceinline__ float tanh_f(float x) { return 2.0f / (1.0f + __expf(-2.0f * x)) - 1.0f; }

__device__ __forceinline__ half8 loadw8(const float* p) {
    const float4* q = (const float4*)p;
    float4 a = q[0], b = q[1];
    half8 r;
    r[0] = (_Float16)a.x; r[1] = (_Float16)a.y; r[2] = (_Float16)a.z; r[3] = (_Float16)a.w;
    r[4] = (_Float16)b.x; r[5] = (_Float16)b.y; r[6] = (_Float16)b.z; r[7] = (_Float16)b.w;
    return r;
}

__global__ void __launch_bounds__(NTHREADS)
lstm2_fused(const float* __restrict__ x,
            const float* __restrict__ Wih0, const float* __restrict__ Whh0,
            const float* __restrict__ bih0, const float* __restrict__ bhh0,
            const float* __restrict__ Wih1, const float* __restrict__ Whh1,
            const float* __restrict__ bih1, const float* __restrict__ bhh1,
            const float* __restrict__ fcw,  const float* __restrict__ fcb,
            float* __restrict__ out)
{
    // A0: [x_t (k 0..31) | h1_{t-1} (k 32..95) | pad]   (16 rows x 128 k, fp16, swizzled)
    // A1: [h1_t (k 0..63) | h2_{t-1} (k 64..127)]
    __shared__ __align__(16) _Float16 A0[16 * 128];
    __shared__ __align__(16) _Float16 A1[16 * 128];
    __shared__ float gatesL[16 * GSTRIDE];
    __shared__ float bias0[G];
    __shared__ float bias1[G];

    const int tid  = threadIdx.x;
    const int wave = tid >> 6;
    const int lane = tid & 63;
    const int lm   = lane & 15;   // MFMA: A row / B (gate) col within 16-tile
    const int lq   = lane >> 4;   // MFMA k-group
    const int ko   = lq * 8;      // k offset within 32-k chunk
    const int b0   = blockIdx.x * BR;
    const int erow = tid >> 6;    // elementwise: batch-local row (= wave)
    const int eu   = tid & 63;    // elementwise: hidden unit

    // ---- init LDS ----
    for (int i = tid; i < 16 * 128; i += NTHREADS) { A0[i] = (_Float16)0.0f; A1[i] = (_Float16)0.0f; }
    if (tid < G) bias0[tid]     = bih0[tid]     + bhh0[tid];
    else         bias1[tid - G] = bih1[tid - G] + bhh1[tid - G];
    __syncthreads();

    // ---- stage x_0 ----
    if (tid < BR * IN0) {
        int xr = tid >> 5, xk = tid & 31;
        A0[aidx(xr, xk)] = (_Float16)x[(size_t)(b0 + xr) * (T_STEPS * IN0) + xk];
    }

    // ---- weights -> register B-fragments (layout: lane holds gate col lm of its
    // tile, k elements kbase + 8*lq + i, matching the A-side k mapping) ----
    half8 bf0[2][3], bf1[2][4];
    #pragma unroll
    for (int tile = 0; tile < 2; ++tile) {
        int j = (wave * 2 + tile) * 16 + lm;               // global gate index
        bf0[tile][0] = loadw8(Wih0 + j * 32 + ko);          // k 0..31  : x   @ W_ih0
        bf0[tile][1] = loadw8(Whh0 + j * 64 + ko);          // k 32..63 : h1  @ W_hh0[:, 0:32]
        bf0[tile][2] = loadw8(Whh0 + j * 64 + 32 + ko);     // k 64..95 : h1  @ W_hh0[:,32:64]
        bf1[tile][0] = loadw8(Wih1 + j * 64 + ko);          // k 0..31  : h1t @ W_ih1[:, 0:32]
        bf1[tile][1] = loadw8(Wih1 + j * 64 + 32 + ko);     // k 32..63 : h1t @ W_ih1[:,32:64]
        bf1[tile][2] = loadw8(Whh1 + j * 64 + ko);          // k 64..95 : h2  @ W_hh1[:, 0:32]
        bf1[tile][3] = loadw8(Whh1 + j * 64 + 32 + ko);     // k 96..127: h2  @ W_hh1[:,32:64]
    }

    float c1 = 0.0f, c2 = 0.0f;
    __syncthreads();

    #pragma unroll 1
    for (int t = 0; t < T_STEPS; ++t) {
        // ======== layer 0: gates0 = [x_t | h1] @ W0^T + bias0 ========
        half8 a0[3];
        #pragma unroll
        for (int c = 0; c < 3; ++c)
            a0[c] = *(const half8*)&A0[aidx(lm, c * 32 + ko)];
        f32x4 acc[2];
        #pragma unroll
        for (int tile = 0; tile < 2; ++tile) {
            float bv = bias0[(wave * 2 + tile) * 16 + lm];
            acc[tile][0] = bv; acc[tile][1] = bv; acc[tile][2] = bv; acc[tile][3] = bv;
            #pragma unroll
            for (int c = 0; c < 3; ++c)
                acc[tile] = __builtin_amdgcn_mfma_f32_16x16x32_f16(a0[c], bf0[tile][c], acc[tile], 0, 0, 0);
        }
        // C layout: col = lane&15, row = 4*(lane>>4)+reg -> rows 0..7 live in lq<2
        if (lq < 2) {
            #pragma unroll
            for (int tile = 0; tile < 2; ++tile)
                #pragma unroll
                for (int r = 0; r < 4; ++r)
                    gatesL[(lq * 4 + r) * GSTRIDE + (wave * 2 + tile) * 16 + lm] = acc[tile][r];
        }
        __syncthreads();

        // ======== layer 0 elementwise (one (row,unit) pair per thread) ========
        {
            float gi = gatesL[erow * GSTRIDE + eu];
            float gf = gatesL[erow * GSTRIDE + 64 + eu];
            float gg = gatesL[erow * GSTRIDE + 128 + eu];
            float go = gatesL[erow * GSTRIDE + 192 + eu];
            float iv = sigm(gi), fv = sigm(gf);
            float gv = tanh_f(gg), ov = sigm(go);
            c1 = fv * c1 + iv * gv;
            float h1 = ov * tanh_f(c1);
            _Float16 hh = (_Float16)h1;
            A0[aidx(erow, 32 + eu)] = hh;   // recurrent input for layer0, step t+1
            A1[aidx(erow, eu)]      = hh;   // input for layer1, step t
        }
        // prefetch x_{t+1}
        if (t + 1 < T_STEPS && tid < BR * IN0) {
            int xr = tid >> 5, xk = tid & 31;
            A0[aidx(xr, xk)] = (_Float16)x[(size_t)(b0 + xr) * (T_STEPS * IN0) + (t + 1) * IN0 + xk];
        }
        __syncthreads();

        // ======== layer 1: gates1 = [h1_t | h2] @ W1^T + bias1 ========
        half8 a1[4];
        #pragma unroll
        for (int c = 0; c < 4; ++c)
            a1[c] = *(const half8*)&A1[aidx(lm, c * 32 + ko)];
        #pragma unroll
        for (int tile = 0; tile < 2; ++tile) {
            float bv = bias1[(wave * 2 + tile) * 16 + lm];
            acc[tile][0] = bv; acc[tile][1] = bv; acc[tile][2] = bv; acc[tile][3] = bv;
            #pragma unroll
            for (int c = 0; c < 4; ++c)
                acc[tile] = __builtin_amdgcn_mfma_f32_16x16x32_f16(a1[c], bf1[tile][c], acc[tile], 0, 0, 0);
        }
        if (lq < 2) {
            #pragma unroll
            for (int tile = 0; tile < 2; ++tile)
                #pragma unroll
                for (int r = 0; r < 4; ++r)
                    gatesL[(lq * 4 + r) * GSTRIDE + (wave * 2 + tile) * 16 + lm] = acc[tile][r];
        }
        __syncthreads();

        // ======== layer 1 elementwise ========
        {
            float gi = gatesL[erow * GSTRIDE + eu];
            float gf = gatesL[erow * GSTRIDE + 64 + eu];
            float gg = gatesL[erow * GSTRIDE + 128 + eu];
            float go = gatesL[erow * GSTRIDE + 192 + eu];
            float iv = sigm(gi), fv = sigm(gf);
            float gv = tanh_f(gg), ov = sigm(go);
            c2 = fv * c2 + iv * gv;
            float h2 = ov * tanh_f(c2);
            A1[aidx(erow, 64 + eu)] = (_Float16)h2;        // recurrent input, step t+1
            if (t == T_STEPS - 1)
                gatesL[erow * GSTRIDE + eu] = h2;          // stash final h2 (fp32) for FC
        }
        __syncthreads();
    }

    // ======== final FC: out[b][o] = h2_final . fc_w[o] + fc_b[o] ========
    if (tid < BR * 2) {
        int row = tid >> 1, o = tid & 1;
        float a = fcb[o];
        #pragma unroll 1
        for (int u = 0; u < H; ++u)
            a = fmaf(gatesL[row * GSTRIDE + u], fcw[o * H + u], a);
        out[(b0 + row) * 2 + o] = a;
    }
}

extern "C" void kernel_launch(void* const* d_in, const int* in_sizes, int n_in,
                              void* d_out, int out_size, void* d_ws, size_t ws_size,
                              hipStream_t stream) {
    const float* x    = (const float*)d_in[0];
    const float* Wih0 = (const float*)d_in[1];
    const float* Whh0 = (const float*)d_in[2];
    const float* bih0 = (const float*)d_in[3];
    const float* bhh0 = (const float*)d_in[4];
    const float* Wih1 = (const float*)d_in[5];
    const float* Whh1 = (const float*)d_in[6];
    const float* bih1 = (const float*)d_in[7];
    const float* bhh1 = (const float*)d_in[8];
    const float* fcw  = (const float*)d_in[9];
    const float* fcb  = (const float*)d_in[10];
    float* out = (float*)d_out;

    dim3 grid(BATCH / BR);      // 256 blocks -> one per CU
    dim3 block(NTHREADS);
    hipLaunchKernelGGL(lstm2_fused, grid, block, 0, stream,
                       x, Wih0, Whh0, bih0, bhh0, Wih1, Whh1, bih1, bhh1, fcw, fcb, out);
}

// Round 2
// 940.305 us; speedup vs baseline: 1.0870x; 1.0870x over previous
//
#include <hip/hip_runtime.h>

#define T_STEPS 512
#define BATCH   2048
#define IN0     32
#define H       64
#define G       256      // 4*H gates
#define BR      4        // batch rows per block (rows 4..15 of MFMA tile are zero padding)
#define NTHREADS 512
#define GSTRIDE 260      // padded row stride for gates LDS (breaks bank conflicts)

typedef _Float16 half8 __attribute__((ext_vector_type(8)));
typedef float    f32x4 __attribute__((ext_vector_type(4)));

// Swizzled index into A buffers ([16 rows][128 k] fp16). Row stride is 256 B ->
// XOR row bits into the 16B-slot bits so ds_read_b128 across rows is conflict-free.
__device__ __forceinline__ int aidx(int m, int k) { return m * 128 + (k ^ (m << 3)); }

__device__ __forceinline__ float sigm(float x)   { return 1.0f / (1.0f + __expf(-x)); }
__device__ __forceinline__ float tanh_f(float x) { return 2.0f / (1.0f + __expf(-2.0f * x)) - 1.0f; }

__device__ __forceinline__ half8 loadw8(const float* p) {
    const float4* q = (const float4*)p;
    float4 a = q[0], b = q[1];
    half8 r;
    r[0] = (_Float16)a.x; r[1] = (_Float16)a.y; r[2] = (_Float16)a.z; r[3] = (_Float16)a.w;
    r[4] = (_Float16)b.x; r[5] = (_Float16)b.y; r[6] = (_Float16)b.z; r[7] = (_Float16)b.w;
    return r;
}

__global__ void __launch_bounds__(NTHREADS)
lstm2_fused(const float* __restrict__ x,
            const float* __restrict__ Wih0, const float* __restrict__ Whh0,
            const float* __restrict__ bih0, const float* __restrict__ bhh0,
            const float* __restrict__ Wih1, const float* __restrict__ Whh1,
            const float* __restrict__ bih1, const float* __restrict__ bhh1,
            const float* __restrict__ fcw,  const float* __restrict__ fcb,
            float* __restrict__ out)
{
    // A0: [x_t (k 0..31) | h1_{t-1} (k 32..95) | pad]   (16 rows x 128 k, fp16, swizzled)
    // A1: [h1_t (k 0..63) | h2_{t-1} (k 64..127)]
    __shared__ __align__(16) _Float16 A0[16 * 128];
    __shared__ __align__(16) _Float16 A1[16 * 128];
    __shared__ float gatesL[16 * GSTRIDE];
    __shared__ float bias0[G];
    __shared__ float bias1[G];

    const int tid  = threadIdx.x;
    const int wave = tid >> 6;
    const int lane = tid & 63;
    const int lm   = lane & 15;   // MFMA: A row / B (gate) col within 16-tile
    const int lq   = lane >> 4;   // MFMA k-group
    const int ko   = lq * 8;      // k offset within 32-k chunk
    const int b0   = blockIdx.x * BR;
    const int erow = tid >> 6;    // elementwise: batch-local row (tid<256: 0..3)
    const int eu   = tid & 63;    // elementwise: hidden unit

    // ---- init LDS ----
    for (int i = tid; i < 16 * 128; i += NTHREADS) { A0[i] = (_Float16)0.0f; A1[i] = (_Float16)0.0f; }
    if (tid < G) bias0[tid]     = bih0[tid]     + bhh0[tid];
    else         bias1[tid - G] = bih1[tid - G] + bhh1[tid - G];
    __syncthreads();

    // ---- stage x_0 ----
    if (tid < BR * IN0) {
        int xr = tid >> 5, xk = tid & 31;
        A0[aidx(xr, xk)] = (_Float16)x[(size_t)(b0 + xr) * (T_STEPS * IN0) + xk];
    }

    // ---- weights -> register B-fragments (layout: lane holds gate col lm of its
    // tile, k elements kbase + 8*lq + i, matching the A-side k mapping) ----
    half8 bf0[2][3], bf1[2][4];
    #pragma unroll
    for (int tile = 0; tile < 2; ++tile) {
        int j = (wave * 2 + tile) * 16 + lm;               // global gate index
        bf0[tile][0] = loadw8(Wih0 + j * 32 + ko);          // k 0..31  : x   @ W_ih0
        bf0[tile][1] = loadw8(Whh0 + j * 64 + ko);          // k 32..63 : h1  @ W_hh0[:, 0:32]
        bf0[tile][2] = loadw8(Whh0 + j * 64 + 32 + ko);     // k 64..95 : h1  @ W_hh0[:,32:64]
        bf1[tile][0] = loadw8(Wih1 + j * 64 + ko);          // k 0..31  : h1t @ W_ih1[:, 0:32]
        bf1[tile][1] = loadw8(Wih1 + j * 64 + 32 + ko);     // k 32..63 : h1t @ W_ih1[:,32:64]
        bf1[tile][2] = loadw8(Whh1 + j * 64 + ko);          // k 64..95 : h2  @ W_hh1[:, 0:32]
        bf1[tile][3] = loadw8(Whh1 + j * 64 + 32 + ko);     // k 96..127: h2  @ W_hh1[:,32:64]
    }

    float c1 = 0.0f, c2 = 0.0f;
    __syncthreads();

    #pragma unroll 1
    for (int t = 0; t < T_STEPS; ++t) {
        // ======== layer 0: gates0 = [x_t | h1] @ W0^T + bias0 ========
        half8 a0[3];
        #pragma unroll
        for (int c = 0; c < 3; ++c)
            a0[c] = *(const half8*)&A0[aidx(lm, c * 32 + ko)];
        f32x4 acc[2];
        #pragma unroll
        for (int tile = 0; tile < 2; ++tile) {
            float bv = bias0[(wave * 2 + tile) * 16 + lm];
            acc[tile][0] = bv; acc[tile][1] = bv; acc[tile][2] = bv; acc[tile][3] = bv;
            #pragma unroll
            for (int c = 0; c < 3; ++c)
                acc[tile] = __builtin_amdgcn_mfma_f32_16x16x32_f16(a0[c], bf0[tile][c], acc[tile], 0, 0, 0);
        }
        // C layout: col = lane&15, row = 4*(lane>>4)+reg -> rows 0..3 live in lq==0
        if (lq == 0) {
            #pragma unroll
            for (int tile = 0; tile < 2; ++tile)
                #pragma unroll
                for (int r = 0; r < BR; ++r)
                    gatesL[r * GSTRIDE + (wave * 2 + tile) * 16 + lm] = acc[tile][r];
        }
        __syncthreads();

        // ======== layer 0 elementwise (one (row,unit) pair per thread, tid<256) ========
        if (tid < BR * H) {
            float gi = gatesL[erow * GSTRIDE + eu];
            float gf = gatesL[erow * GSTRIDE + 64 + eu];
            float gg = gatesL[erow * GSTRIDE + 128 + eu];
            float go = gatesL[erow * GSTRIDE + 192 + eu];
            float iv = sigm(gi), fv = sigm(gf);
            float gv = tanh_f(gg), ov = sigm(go);
            c1 = fv * c1 + iv * gv;
            float h1 = ov * tanh_f(c1);
            _Float16 hh = (_Float16)h1;
            A0[aidx(erow, 32 + eu)] = hh;   // recurrent input for layer0, step t+1
            A1[aidx(erow, eu)]      = hh;   // input for layer1, step t
        }
        // prefetch x_{t+1}
        if (t + 1 < T_STEPS && tid >= 256 && tid < 256 + BR * IN0) {
            int xr = (tid - 256) >> 5, xk = tid & 31;
            A0[aidx(xr, xk)] = (_Float16)x[(size_t)(b0 + xr) * (T_STEPS * IN0) + (t + 1) * IN0 + xk];
        }
        __syncthreads();

        // ======== layer 1: gates1 = [h1_t | h2] @ W1^T + bias1 ========
        half8 a1[4];
        #pragma unroll
        for (int c = 0; c < 4; ++c)
            a1[c] = *(const half8*)&A1[aidx(lm, c * 32 + ko)];
        #pragma unroll
        for (int tile = 0; tile < 2; ++tile) {
            float bv = bias1[(wave * 2 + tile) * 16 + lm];
            acc[tile][0] = bv; acc[tile][1] = bv; acc[tile][2] = bv; acc[tile][3] = bv;
            #pragma unroll
            for (int c = 0; c < 4; ++c)
                acc[tile] = __builtin_amdgcn_mfma_f32_16x16x32_f16(a1[c], bf1[tile][c], acc[tile], 0, 0, 0);
        }
        if (lq == 0) {
            #pragma unroll
            for (int tile = 0; tile < 2; ++tile)
                #pragma unroll
                for (int r = 0; r < BR; ++r)
                    gatesL[r * GSTRIDE + (wave * 2 + tile) * 16 + lm] = acc[tile][r];
        }
        __syncthreads();

        // ======== layer 1 elementwise ========
        if (tid < BR * H) {
            float gi = gatesL[erow * GSTRIDE + eu];
            float gf = gatesL[erow * GSTRIDE + 64 + eu];
            float gg = gatesL[erow * GSTRIDE + 128 + eu];
            float go = gatesL[erow * GSTRIDE + 192 + eu];
            float iv = sigm(gi), fv = sigm(gf);
            float gv = tanh_f(gg), ov = sigm(go);
            c2 = fv * c2 + iv * gv;
            float h2 = ov * tanh_f(c2);
            A1[aidx(erow, 64 + eu)] = (_Float16)h2;        // recurrent input, step t+1
            if (t == T_STEPS - 1)
                gatesL[erow * GSTRIDE + eu] = h2;          // stash final h2 (fp32) for FC
        }
        __syncthreads();
    }

    // ======== final FC: out[b][o] = h2_final . fc_w[o] + fc_b[o] ========
    if (tid < BR * 2) {
        int row = tid >> 1, o = tid & 1;
        float a = fcb[o];
        #pragma unroll 1
        for (int u = 0; u < H; ++u)
            a = fmaf(gatesL[row * GSTRIDE + u], fcw[o * H + u], a);
        out[(b0 + row) * 2 + o] = a;
    }
}

extern "C" void kernel_launch(void* const* d_in, const int* in_sizes, int n_in,
                              void* d_out, int out_size, void* d_ws, size_t ws_size,
                              hipStream_t stream) {
    const float* x    = (const float*)d_in[0];
    const float* Wih0 = (const float*)d_in[1];
    const float* Whh0 = (const float*)d_in[2];
    const float* bih0 = (const float*)d_in[3];
    const float* bhh0 = (const float*)d_in[4];
    const float* Wih1 = (const float*)d_in[5];
    const float* Whh1 = (const float*)d_in[6];
    const float* bih1 = (const float*)d_in[7];
    const float* bhh1 = (const float*)d_in[8];
    const float* fcw  = (const float*)d_in[9];
    const float* fcb  = (const float*)d_in[10];
    float* out = (float*)d_out;

    dim3 grid(BATCH / BR);      // 512 blocks -> 2 per CU: overlapping barrier domains
    dim3 block(NTHREADS);
    hipLaunchKernelGGL(lstm2_fused, grid, block, 0, stream,
                       x, Wih0, Whh0, bih0, bhh0, Wih1, Whh1, bih1, bhh1, fcw, fcb, out);
}

// Round 5
// 930.728 us; speedup vs baseline: 1.0982x; 1.0103x over previous
//
#include <hip/hip_runtime.h>

#define TT   512
#define IN0_ 32
#define HH   64
#define BR   16          // batch rows per block (full 16x16 MFMA tile, no padding)
#define NT   512         // 8 waves: waves 0-3 = layer0, waves 4-7 = layer1
#define AST  256         // A-buffer k-stride: two 128-wide halves = phase double-buffer

typedef _Float16 half8 __attribute__((ext_vector_type(8)));
typedef float    f32x4 __attribute__((ext_vector_type(4)));

// Swizzled index into A buffers ([16 rows][256 k] fp16). XOR row bits into the
// 16B-slot bits; each 128-k half is closed under the swizzle (bits 3-6 only).
__device__ __forceinline__ int aidx(int m, int k) { return m * AST + (k ^ (m << 3)); }

__device__ __forceinline__ float sigm(float x)    { return 1.0f / (1.0f + __expf(-x)); }
__device__ __forceinline__ float tanhf_(float x)  { return 2.0f / (1.0f + __expf(-2.0f * x)) - 1.0f; }

__device__ __forceinline__ half8 loadw8(const float* p) {
    const float4* q = (const float4*)p;
    float4 a = q[0], b = q[1];
    half8 r;
    r[0] = (_Float16)a.x; r[1] = (_Float16)a.y; r[2] = (_Float16)a.z; r[3] = (_Float16)a.w;
    r[4] = (_Float16)b.x; r[5] = (_Float16)b.y; r[6] = (_Float16)b.z; r[7] = (_Float16)b.w;
    return r;
}

// Barrier WITHOUT vmcnt drain: only LDS (lgkm) ops must be visible across the
// barrier; the in-flight x global prefetch must NOT be drained. No global
// stores happen inside the loop, so skipping vmcnt(0) is safe.
#define BAR() asm volatile("s_waitcnt lgkmcnt(0)\n\ts_barrier" ::: "memory")

__global__ void __launch_bounds__(NT, 2)
lstm2_fused(const float* __restrict__ x,
            const float* __restrict__ Wih0, const float* __restrict__ Whh0,
            const float* __restrict__ bih0, const float* __restrict__ bhh0,
            const float* __restrict__ Wih1, const float* __restrict__ Whh1,
            const float* __restrict__ bih1, const float* __restrict__ bhh1,
            const float* __restrict__ fcw,  const float* __restrict__ fcb,
            float* __restrict__ out)
{
    // A0 half: [x (k 0..31) | h1 (k 32..95) | free]  A1 half: [h1t (0..63) | h2 (64..127)]
    __shared__ __align__(16) _Float16 A0[16 * AST];
    __shared__ __align__(16) _Float16 A1[16 * AST];
    __shared__ float fin[16 * 68];

    const int tid  = threadIdx.x;
    const int wave = tid >> 6;
    const int lane = tid & 63;
    const int lm   = lane & 15;       // MFMA col (gate unit) / A row
    const int lq   = lane >> 4;       // MFMA k-group; acc rows 4*lq..4*lq+3
    const int ko   = lq * 8;
    const int b0   = blockIdx.x * BR;
    const bool isL0 = (wave < 4);
    const int w4   = wave & 3;
    const int u    = w4 * 16 + lm;    // this lane's hidden unit (per layer group)

    for (int i = tid; i < 16 * AST; i += NT) { A0[i] = (_Float16)0.0f; A1[i] = (_Float16)0.0f; }
    __syncthreads();

    // ---- weights -> register B-fragments; 4 gate tiles (i,f,g,o) of 16 units each ----
    half8 bf[16] = {};
    float bs[4];
    if (isL0) {
        #pragma unroll
        for (int g = 0; g < 4; ++g) {
            int j = g * 64 + u;                              // PyTorch gate order i,f,g,o
            bf[g]      = loadw8(Wih0 + j * IN0_ + ko);       // x chunk (k 0..31)
            bf[4 + g]  = loadw8(Whh0 + j * HH + ko);         // h1 lo (k 32..63)
            bf[8 + g]  = loadw8(Whh0 + j * HH + 32 + ko);    // h1 hi (k 64..95)
            bs[g] = bih0[j] + bhh0[j];
        }
    } else {
        #pragma unroll
        for (int g = 0; g < 4; ++g) {
            int j = g * 64 + u;
            bf[g]      = loadw8(Wih1 + j * HH + ko);         // h1t lo (k 0..31)
            bf[4 + g]  = loadw8(Wih1 + j * HH + 32 + ko);    // h1t hi (k 32..63)
            bf[8 + g]  = loadw8(Whh1 + j * HH + ko);         // h2 lo  (k 64..95)
            bf[12 + g] = loadw8(Whh1 + j * HH + 32 + ko);    // h2 hi  (k 96..127)
            bs[g] = bih1[j] + bhh1[j];
        }
    }

    // ---- x staging pipeline (L0 waves, 256 threads: one float2 per thread/step) ----
    const int prow = tid >> 4;                 // 0..15 for tid<256
    const int pk   = (tid & 15) * 2;
    const float* xbase = x + (size_t)(b0 + (prow & 15)) * (TT * IN0_) + pk;
    float2 xcur, xnxt;
    if (isL0) {
        float2 x0 = *(const float2*)xbase;     // t=0 -> buf0 directly
        int phys = aidx(prow, pk);
        A0[phys] = (_Float16)x0.x; A0[phys + 1] = (_Float16)x0.y;
        xcur = *(const float2*)(xbase + 1 * IN0_);   // x_1
        xnxt = *(const float2*)(xbase + 2 * IN0_);   // x_2
    }

    float c1[4] = {0, 0, 0, 0}, c2[4] = {0, 0, 0, 0}, h2r[4] = {0, 0, 0, 0};
    __syncthreads();

    // ---- main loop: phase ph: L0 computes h1_ph, L1 computes h2_{ph-1} ----
    #pragma unroll 1
    for (int ph = 0; ph <= TT; ++ph) {
        const int bo  = (ph & 1) << 7;    // read half
        const int nbo = bo ^ 128;         // write half
        if (isL0) {
            if (ph < TT) {
                half8 ax  = *(const half8*)&A0[aidx(lm, bo + ko)];
                half8 ah0 = *(const half8*)&A0[aidx(lm, bo + 32 + ko)];
                half8 ah1 = *(const half8*)&A0[aidx(lm, bo + 64 + ko)];
                f32x4 acc[4];
                #pragma unroll
                for (int g = 0; g < 4; ++g) { acc[g][0] = bs[g]; acc[g][1] = bs[g]; acc[g][2] = bs[g]; acc[g][3] = bs[g]; }
                #pragma unroll
                for (int g = 0; g < 4; ++g) acc[g] = __builtin_amdgcn_mfma_f32_16x16x32_f16(ax,  bf[g],     acc[g], 0, 0, 0);
                #pragma unroll
                for (int g = 0; g < 4; ++g) acc[g] = __builtin_amdgcn_mfma_f32_16x16x32_f16(ah0, bf[4 + g], acc[g], 0, 0, 0);
                #pragma unroll
                for (int g = 0; g < 4; ++g) acc[g] = __builtin_amdgcn_mfma_f32_16x16x32_f16(ah1, bf[8 + g], acc[g], 0, 0, 0);
                #pragma unroll
                for (int r = 0; r < 4; ++r) {
                    float iv = sigm(acc[0][r]), fv = sigm(acc[1][r]);
                    float gv = tanhf_(acc[2][r]), ov = sigm(acc[3][r]);
                    c1[r] = fv * c1[r] + iv * gv;
                    float h1 = ov * tanhf_(c1[r]);
                    _Float16 hh = (_Float16)h1;
                    int row = 4 * lq + r;
                    A0[aidx(row, nbo + 32 + u)] = hh;   // layer0 recurrent, phase ph+1
                    A1[aidx(row, nbo + u)]      = hh;   // layer1 input, phase ph+1
                }
                // stage x_{ph+1} into write half; advance 2-deep prefetch
                int phys = aidx(prow, nbo + pk);
                A0[phys]     = (_Float16)xcur.x;
                A0[phys + 1] = (_Float16)xcur.y;
                xcur = xnxt;
                int tn = (ph + 3 < TT) ? (ph + 3) : (TT - 1);
                xnxt = *(const float2*)(xbase + (size_t)tn * IN0_);
            }
        } else {
            if (ph >= 1) {
                half8 a0c = *(const half8*)&A1[aidx(lm, bo + ko)];
                half8 a1c = *(const half8*)&A1[aidx(lm, bo + 32 + ko)];
                half8 a2c = *(const half8*)&A1[aidx(lm, bo + 64 + ko)];
                half8 a3c = *(const half8*)&A1[aidx(lm, bo + 96 + ko)];
                f32x4 acc[4];
                #pragma unroll
                for (int g = 0; g < 4; ++g) { acc[g][0] = bs[g]; acc[g][1] = bs[g]; acc[g][2] = bs[g]; acc[g][3] = bs[g]; }
                #pragma unroll
                for (int g = 0; g < 4; ++g) acc[g] = __builtin_amdgcn_mfma_f32_16x16x32_f16(a0c, bf[g],      acc[g], 0, 0, 0);
                #pragma unroll
                for (int g = 0; g < 4; ++g) acc[g] = __builtin_amdgcn_mfma_f32_16x16x32_f16(a1c, bf[4 + g],  acc[g], 0, 0, 0);
                #pragma unroll
                for (int g = 0; g < 4; ++g) acc[g] = __builtin_amdgcn_mfma_f32_16x16x32_f16(a2c, bf[8 + g],  acc[g], 0, 0, 0);
                #pragma unroll
                for (int g = 0; g < 4; ++g) acc[g] = __builtin_amdgcn_mfma_f32_16x16x32_f16(a3c, bf[12 + g], acc[g], 0, 0, 0);
                #pragma unroll
                for (int r = 0; r < 4; ++r) {
                    float iv = sigm(acc[0][r]), fv = sigm(acc[1][r]);
                    float gv = tanhf_(acc[2][r]), ov = sigm(acc[3][r]);
                    c2[r] = fv * c2[r] + iv * gv;
                    float h2 = ov * tanhf_(c2[r]);
                    h2r[r] = h2;
                    A1[aidx(4 * lq + r, nbo + 64 + u)] = (_Float16)h2;  // recurrent, phase ph+1
                }
            }
        }
        BAR();
    }

    // ---- FC epilogue: h2_final lives in L1 waves' h2r ----
    if (!isL0) {
        #pragma unroll
        for (int r = 0; r < 4; ++r) fin[(4 * lq + r) * 68 + u] = h2r[r];
    }
    __syncthreads();
    if (tid < 32) {
        int row = tid >> 1, o = tid & 1;
        float a = fcb[o];
        #pragma unroll 1
        for (int u2 = 0; u2 < HH; ++u2)
            a = fmaf(fin[row * 68 + u2], fcw[o * HH + u2], a);
        out[(size_t)(b0 + row) * 2 + o] = a;
    }
}

extern "C" void kernel_launch(void* const* d_in, const int* in_sizes, int n_in,
                              void* d_out, int out_size, void* d_ws, size_t ws_size,
                              hipStream_t stream) {
    const float* x    = (const float*)d_in[0];
    const float* Wih0 = (const float*)d_in[1];
    const float* Whh0 = (const float*)d_in[2];
    const float* bih0 = (const float*)d_in[3];
    const float* bhh0 = (const float*)d_in[4];
    const float* Wih1 = (const float*)d_in[5];
    const float* Whh1 = (const float*)d_in[6];
    const float* bih1 = (const float*)d_in[7];
    const float* bhh1 = (const float*)d_in[8];
    const float* fcw  = (const float*)d_in[9];
    const float* fcb  = (const float*)d_in[10];
    float* out = (float*)d_out;

    dim3 grid(2048 / BR);    // 128 blocks; latency-bound -> CU count irrelevant
    dim3 block(NT);
    hipLaunchKernelGGL(lstm2_fused, grid, block, 0, stream,
                       x, Wih0, Whh0, bih0, bhh0, Wih1, Whh1, bih1, bhh1, fcw, fcb, out);
}

// Round 7
// 576.115 us; speedup vs baseline: 1.7741x; 1.6155x over previous
//
#include <hip/hip_runtime.h>

#define TT   512
#define IN0_ 32
#define HH   64
#define BR   16          // batch rows per block (full 16x16 MFMA tile)
#define NT   512         // 8 waves: 0-3 = layer0, 4-7 = layer1
#define AST  256         // A-buffer k-stride: two 128-wide halves = phase double-buffer

typedef _Float16 half8 __attribute__((ext_vector_type(8)));
typedef float    f32x4 __attribute__((ext_vector_type(4)));

// Swizzled element index ([16 rows][256 k] fp16). Swizzle bits are 3..6 only, so
// aidx(m, bo + k) == aidx(m, k) + bo for bo in {0,128}: bo folds to an imm offset.
__device__ __forceinline__ int aidx(int m, int k) { return m * AST + (k ^ (m << 3)); }

// Fast activations: v_exp + v_rcp only (no IEEE division sequence).
__device__ __forceinline__ float sigm(float x)   { return __builtin_amdgcn_rcpf(1.0f + __expf(-x)); }
__device__ __forceinline__ float tanhf_(float x) { return 1.0f - 2.0f * __builtin_amdgcn_rcpf(1.0f + __expf(2.0f * x)); }

__device__ __forceinline__ half8 loadw8(const float* p) {
    const float4* q = (const float4*)p;
    float4 a = q[0], b = q[1];
    half8 r;
    r[0] = (_Float16)a.x; r[1] = (_Float16)a.y; r[2] = (_Float16)a.z; r[3] = (_Float16)a.w;
    r[4] = (_Float16)b.x; r[5] = (_Float16)b.y; r[6] = (_Float16)b.z; r[7] = (_Float16)b.w;
    return r;
}

// Barrier WITHOUT vmcnt drain: keeps the global x prefetch in flight.
#define BAR() asm volatile("s_waitcnt lgkmcnt(0)\n\ts_barrier" ::: "memory")

__global__ void __launch_bounds__(NT, 2)
lstm2_fused(const float* __restrict__ x,
            const float* __restrict__ Wih0, const float* __restrict__ Whh0,
            const float* __restrict__ bih0, const float* __restrict__ bhh0,
            const float* __restrict__ Wih1, const float* __restrict__ Whh1,
            const float* __restrict__ bih1, const float* __restrict__ bhh1,
            const float* __restrict__ fcw,  const float* __restrict__ fcb,
            float* __restrict__ out)
{
    // A0 half: [x_t (k 0..31) | h1 (k 32..95) | free]; L1 reads h1 from A0 directly.
    // A1 half: [h2 (k 0..63) | free]
    __shared__ __align__(16) _Float16 A0[16 * AST];
    __shared__ __align__(16) _Float16 A1[16 * AST];
    __shared__ float fin[16 * 68];

    const int tid  = threadIdx.x;
    const int wave = tid >> 6;
    const int lane = tid & 63;
    const int lm   = lane & 15;       // MFMA col (gate unit) / A row
    const int lq   = lane >> 4;       // MFMA k-group; acc rows 4*lq..4*lq+3
    const int ko   = lq * 8;
    const int b0   = blockIdx.x * BR;
    const bool isL0 = (wave < 4);
    const int w4   = wave & 3;
    const int u    = w4 * 16 + lm;    // this lane's hidden unit (per layer group)

    // ---- precomputed LDS element bases (parity added as +bo/+nbo literal) ----
    const int ar0 = aidx(lm, ko);            // A0: x chunk   | A1: h2 lo
    const int ar1 = aidx(lm, 32 + ko);       // A0: h1 lo     | A1: h2 hi
    const int ar2 = aidx(lm, 64 + ko);       // A0: h1 hi
    int wA[4];                               // per-row h store bases
    #pragma unroll
    for (int r = 0; r < 4; ++r) {
        int row = 4 * lq + r;
        wA[r] = isL0 ? aidx(row, 32 + u)     // h1 -> A0
                     : aidx(row, u);         // h2 -> A1
    }

    for (int i = tid; i < 16 * AST; i += NT) { A0[i] = (_Float16)0.0f; A1[i] = (_Float16)0.0f; }
    __syncthreads();

    // ---- weights -> register B-fragments; 4 gate tiles (i,f,g,o) of 16 units ----
    half8 bf[16] = {};
    float bs[4];
    if (isL0) {
        #pragma unroll
        for (int g = 0; g < 4; ++g) {
            int j = g * 64 + u;                              // PyTorch gate order i,f,g,o
            bf[g]      = loadw8(Wih0 + j * IN0_ + ko);       // x chunk (k 0..31)
            bf[4 + g]  = loadw8(Whh0 + j * HH + ko);         // h1 lo (k 32..63)
            bf[8 + g]  = loadw8(Whh0 + j * HH + 32 + ko);    // h1 hi (k 64..95)
            bs[g] = bih0[j] + bhh0[j];
        }
    } else {
        #pragma unroll
        for (int g = 0; g < 4; ++g) {
            int j = g * 64 + u;
            bf[g]      = loadw8(Wih1 + j * HH + ko);         // h1t lo (A0 k 32..63)
            bf[4 + g]  = loadw8(Wih1 + j * HH + 32 + ko);    // h1t hi (A0 k 64..95)
            bf[8 + g]  = loadw8(Whh1 + j * HH + ko);         // h2 lo  (A1 k 0..31)
            bf[12 + g] = loadw8(Whh1 + j * HH + 32 + ko);    // h2 hi  (A1 k 32..63)
            bs[g] = bih1[j] + bhh1[j];
        }
    }

    // ---- x staging pipeline (L0 waves: 256 threads, one float2 per row-chunk) ----
    const int prow = tid >> 4;                 // 0..15 for tid<256
    const int pk   = (tid & 15) * 2;
    const int xw   = aidx(prow & 15, pk);      // element base; pk even -> 4B aligned
    const float* xbase = x + (size_t)(b0 + (prow & 15)) * (TT * IN0_) + pk;
    float2 xcur, xnxt;
    if (isL0) {
        float2 x0 = *(const float2*)xbase;     // t=0 -> buf half 0 directly
        union { _Float16 h[2]; unsigned v; } up;
        up.h[0] = (_Float16)x0.x; up.h[1] = (_Float16)x0.y;
        *(unsigned*)&A0[xw] = up.v;
        xcur = *(const float2*)(xbase + 1 * IN0_);   // x_1
        xnxt = *(const float2*)(xbase + 2 * IN0_);   // x_2
    }

    float c1[4] = {0, 0, 0, 0}, c2[4] = {0, 0, 0, 0}, h2r[4] = {0, 0, 0, 0};
    __syncthreads();

    // ---- phase bodies: bo is a literal at every call site -> imm LDS offsets ----
    auto phaseL0 = [&](int bo, int ph) {
        const int nbo = bo ^ 128;
        half8 ax  = *(const half8*)&A0[ar0 + bo];
        half8 ah0 = *(const half8*)&A0[ar1 + bo];
        half8 ah1 = *(const half8*)&A0[ar2 + bo];
        f32x4 acc[4];
        #pragma unroll
        for (int g = 0; g < 4; ++g) { acc[g][0] = bs[g]; acc[g][1] = bs[g]; acc[g][2] = bs[g]; acc[g][3] = bs[g]; }
        #pragma unroll
        for (int g = 0; g < 4; ++g) acc[g] = __builtin_amdgcn_mfma_f32_16x16x32_f16(ax,  bf[g],     acc[g], 0, 0, 0);
        #pragma unroll
        for (int g = 0; g < 4; ++g) acc[g] = __builtin_amdgcn_mfma_f32_16x16x32_f16(ah0, bf[4 + g], acc[g], 0, 0, 0);
        #pragma unroll
        for (int g = 0; g < 4; ++g) acc[g] = __builtin_amdgcn_mfma_f32_16x16x32_f16(ah1, bf[8 + g], acc[g], 0, 0, 0);
        #pragma unroll
        for (int r = 0; r < 4; ++r) {
            float iv = sigm(acc[0][r]), fv = sigm(acc[1][r]);
            float gv = tanhf_(acc[2][r]), ov = sigm(acc[3][r]);
            c1[r] = fv * c1[r] + iv * gv;
            float h1 = ov * tanhf_(c1[r]);
            A0[wA[r] + nbo] = (_Float16)h1;          // single store: L1 reads A0 too
        }
        // stage x_{ph+1} into write half (packed b32); advance 2-deep prefetch
        union { _Float16 h[2]; unsigned v; } up;
        up.h[0] = (_Float16)xcur.x; up.h[1] = (_Float16)xcur.y;
        *(unsigned*)&A0[xw + nbo] = up.v;
        xcur = xnxt;
        int tn = ph + 3; if (tn > TT - 1) tn = TT - 1;
        xnxt = *(const float2*)(xbase + (size_t)tn * IN0_);
    };

    auto phaseL1 = [&](int bo) {
        const int nbo = bo ^ 128;
        half8 a0c = *(const half8*)&A0[ar1 + bo];    // h1t lo (from A0!)
        half8 a1c = *(const half8*)&A0[ar2 + bo];    // h1t hi
        half8 a2c = *(const half8*)&A1[ar0 + bo];    // h2 lo
        half8 a3c = *(const half8*)&A1[ar1 + bo];    // h2 hi
        f32x4 acc[4];
        #pragma unroll
        for (int g = 0; g < 4; ++g) { acc[g][0] = bs[g]; acc[g][1] = bs[g]; acc[g][2] = bs[g]; acc[g][3] = bs[g]; }
        #pragma unroll
        for (int g = 0; g < 4; ++g) acc[g] = __builtin_amdgcn_mfma_f32_16x16x32_f16(a0c, bf[g],      acc[g], 0, 0, 0);
        #pragma unroll
        for (int g = 0; g < 4; ++g) acc[g] = __builtin_amdgcn_mfma_f32_16x16x32_f16(a1c, bf[4 + g],  acc[g], 0, 0, 0);
        #pragma unroll
        for (int g = 0; g < 4; ++g) acc[g] = __builtin_amdgcn_mfma_f32_16x16x32_f16(a2c, bf[8 + g],  acc[g], 0, 0, 0);
        #pragma unroll
        for (int g = 0; g < 4; ++g) acc[g] = __builtin_amdgcn_mfma_f32_16x16x32_f16(a3c, bf[12 + g], acc[g], 0, 0, 0);
        #pragma unroll
        for (int r = 0; r < 4; ++r) {
            float iv = sigm(acc[0][r]), fv = sigm(acc[1][r]);
            float gv = tanhf_(acc[2][r]), ov = sigm(acc[3][r]);
            c2[r] = fv * c2[r] + iv * gv;
            float h2 = ov * tanhf_(c2[r]);
            h2r[r] = h2;
            A1[wA[r] + nbo] = (_Float16)h2;
        }
    };

    // ---- main loop: phase ph: L0 computes h1_ph, L1 computes h2_{ph-1} ----
    if (isL0) phaseL0(0, 0);
    BAR();
    #pragma unroll 1
    for (int ph = 1; ph < TT - 1; ph += 2) {
        if (isL0) phaseL0(128, ph); else phaseL1(128);
        BAR();
        if (isL0) phaseL0(0, ph + 1); else phaseL1(0);
        BAR();
    }
    if (isL0) phaseL0(128, TT - 1); else phaseL1(128);   // ph = 511
    BAR();
    if (!isL0) phaseL1(0);                               // ph = 512: final h2

    // ---- FC epilogue ----
    if (!isL0) {
        #pragma unroll
        for (int r = 0; r < 4; ++r) fin[(4 * lq + r) * 68 + u] = h2r[r];
    }
    __syncthreads();
    if (tid < 32) {
        int row = tid >> 1, o = tid & 1;
        float a = fcb[o];
        #pragma unroll 1
        for (int u2 = 0; u2 < HH; ++u2)
            a = fmaf(fin[row * 68 + u2], fcw[o * HH + u2], a);
        out[(size_t)(b0 + row) * 2 + o] = a;
    }
}

extern "C" void kernel_launch(void* const* d_in, const int* in_sizes, int n_in,
                              void* d_out, int out_size, void* d_ws, size_t ws_size,
                              hipStream_t stream) {
    const float* x    = (const float*)d_in[0];
    const float* Wih0 = (const float*)d_in[1];
    const float* Whh0 = (const float*)d_in[2];
    const float* bih0 = (const float*)d_in[3];
    const float* bhh0 = (const float*)d_in[4];
    const float* Wih1 = (const float*)d_in[5];
    const float* Whh1 = (const float*)d_in[6];
    const float* bih1 = (const float*)d_in[7];
    const float* bhh1 = (const float*)d_in[8];
    const float* fcw  = (const float*)d_in[9];
    const float* fcb  = (const float*)d_in[10];
    float* out = (float*)d_out;

    dim3 grid(2048 / BR);    // 128 blocks; latency-bound -> chain length sets wall time
    dim3 block(NT);
    hipLaunchKernelGGL(lstm2_fused, grid, block, 0, stream,
                       x, Wih0, Whh0, bih0, bhh0, Wih1, Whh1, bih1, bhh1, fcw, fcb, out);
}

// Round 8
// 560.748 us; speedup vs baseline: 1.8227x; 1.0274x over previous
//
#include <hip/hip_runtime.h>

#define TT   512
#define IN0_ 32
#define HH   64
#define BR   8           // batch rows per block; rows 8..15 of the 16x16 MFMA tile are padding
#define NT   512         // 8 waves: 0-3 = layer0, 4-7 = layer1
#define AST  256         // A-buffer k-stride: two 128-wide halves = phase double-buffer

typedef _Float16 half8 __attribute__((ext_vector_type(8)));
typedef float    f32x4 __attribute__((ext_vector_type(4)));

// Swizzled element index ([16 rows][256 k] fp16). Swizzle bits are 3..6 only, so
// aidx(m, bo + k) == aidx(m, k) + bo for bo in {0,128}: bo folds to an imm offset.
__device__ __forceinline__ int aidx(int m, int k) { return m * AST + (k ^ (m << 3)); }

// Fast activations: v_exp + v_rcp only (no IEEE division sequence).
__device__ __forceinline__ float sigm(float x)   { return __builtin_amdgcn_rcpf(1.0f + __expf(-x)); }
__device__ __forceinline__ float tanhf_(float x) { return 1.0f - 2.0f * __builtin_amdgcn_rcpf(1.0f + __expf(2.0f * x)); }

__device__ __forceinline__ half8 loadw8(const float* p) {
    const float4* q = (const float4*)p;
    float4 a = q[0], b = q[1];
    half8 r;
    r[0] = (_Float16)a.x; r[1] = (_Float16)a.y; r[2] = (_Float16)a.z; r[3] = (_Float16)a.w;
    r[4] = (_Float16)b.x; r[5] = (_Float16)b.y; r[6] = (_Float16)b.z; r[7] = (_Float16)b.w;
    return r;
}

// Barrier WITHOUT vmcnt drain: keeps the global x prefetch in flight.
#define BAR() asm volatile("s_waitcnt lgkmcnt(0)\n\ts_barrier" ::: "memory")

__global__ void __launch_bounds__(NT, 2)
lstm2_fused(const float* __restrict__ x,
            const float* __restrict__ Wih0, const float* __restrict__ Whh0,
            const float* __restrict__ bih0, const float* __restrict__ bhh0,
            const float* __restrict__ Wih1, const float* __restrict__ Whh1,
            const float* __restrict__ bih1, const float* __restrict__ bhh1,
            const float* __restrict__ fcw,  const float* __restrict__ fcb,
            float* __restrict__ out)
{
    // A0 half: [x_t (k 0..31) | h1 (k 32..95) | free]; L1 reads h1 from A0 directly.
    // A1 half: [h2 (k 0..63) | free]
    __shared__ __align__(16) _Float16 A0[16 * AST];
    __shared__ __align__(16) _Float16 A1[16 * AST];
    __shared__ float fin[16 * 68];

    const int tid  = threadIdx.x;
    const int wave = tid >> 6;
    const int lane = tid & 63;
    const int lm   = lane & 15;       // MFMA col (gate unit) / A row
    const int lq   = lane >> 4;       // MFMA k-group; acc rows 4*lq..4*lq+3
    const int ko   = lq * 8;
    const int b0   = blockIdx.x * BR;
    const bool isL0 = (wave < 4);
    const int w4   = wave & 3;
    const int u    = w4 * 16 + lm;    // this lane's hidden unit (per layer group)

    // ---- precomputed LDS element bases (parity added as +bo/+nbo literal) ----
    const int ar0 = aidx(lm, ko);            // A0: x chunk   | A1: h2 lo
    const int ar1 = aidx(lm, 32 + ko);       // A0: h1 lo     | A1: h2 hi
    const int ar2 = aidx(lm, 64 + ko);       // A0: h1 hi
    int wA[4];                               // per-row h store bases (rows >=8 are padding, harmless)
    #pragma unroll
    for (int r = 0; r < 4; ++r) {
        int row = 4 * lq + r;
        wA[r] = isL0 ? aidx(row, 32 + u)     // h1 -> A0
                     : aidx(row, u);         // h2 -> A1
    }

    for (int i = tid; i < 16 * AST; i += NT) { A0[i] = (_Float16)0.0f; A1[i] = (_Float16)0.0f; }
    __syncthreads();

    // ---- weights -> register B-fragments; 4 gate tiles (i,f,g,o) of 16 units ----
    half8 bf[16] = {};
    float bs[4];
    if (isL0) {
        #pragma unroll
        for (int g = 0; g < 4; ++g) {
            int j = g * 64 + u;                              // PyTorch gate order i,f,g,o
            bf[g]      = loadw8(Wih0 + j * IN0_ + ko);       // x chunk (k 0..31)
            bf[4 + g]  = loadw8(Whh0 + j * HH + ko);         // h1 lo (k 32..63)
            bf[8 + g]  = loadw8(Whh0 + j * HH + 32 + ko);    // h1 hi (k 64..95)
            bs[g] = bih0[j] + bhh0[j];
        }
    } else {
        #pragma unroll
        for (int g = 0; g < 4; ++g) {
            int j = g * 64 + u;
            bf[g]      = loadw8(Wih1 + j * HH + ko);         // h1t lo (A0 k 32..63)
            bf[4 + g]  = loadw8(Wih1 + j * HH + 32 + ko);    // h1t hi (A0 k 64..95)
            bf[8 + g]  = loadw8(Whh1 + j * HH + ko);         // h2 lo  (A1 k 0..31)
            bf[12 + g] = loadw8(Whh1 + j * HH + 32 + ko);    // h2 hi  (A1 k 32..63)
            bs[g] = bih1[j] + bhh1[j];
        }
    }

    // ---- x staging (waves 0-1: 128 threads, one float2 per (row, k-pair)) ----
    const int prow = (tid >> 4) & 7;           // 0..7 for tid<128
    const int pk   = (tid & 15) * 2;
    const int xw   = aidx(prow, pk);           // element base; pk even -> 4B aligned
    const float* xbase = x + (size_t)(b0 + prow) * (TT * IN0_) + pk;
    float2 xcur, xnxt;
    if (wave < 2) {
        float2 x0 = *(const float2*)xbase;     // t=0 -> buf half 0 directly
        union { _Float16 h[2]; unsigned v; } up;
        up.h[0] = (_Float16)x0.x; up.h[1] = (_Float16)x0.y;
        *(unsigned*)&A0[xw] = up.v;
        xcur = *(const float2*)(xbase + 1 * IN0_);   // x_1
        xnxt = *(const float2*)(xbase + 2 * IN0_);   // x_2
    }

    float c1[4] = {0, 0, 0, 0}, c2[4] = {0, 0, 0, 0}, h2r[4] = {0, 0, 0, 0};
    __syncthreads();

    // ---- phase bodies: bo is a literal at every call site -> imm LDS offsets ----
    auto phaseL0 = [&](int bo, int ph) {
        const int nbo = bo ^ 128;
        half8 ax  = *(const half8*)&A0[ar0 + bo];
        half8 ah0 = *(const half8*)&A0[ar1 + bo];
        half8 ah1 = *(const half8*)&A0[ar2 + bo];
        f32x4 acc[4];
        #pragma unroll
        for (int g = 0; g < 4; ++g) { acc[g][0] = bs[g]; acc[g][1] = bs[g]; acc[g][2] = bs[g]; acc[g][3] = bs[g]; }
        #pragma unroll
        for (int g = 0; g < 4; ++g) acc[g] = __builtin_amdgcn_mfma_f32_16x16x32_f16(ax,  bf[g],     acc[g], 0, 0, 0);
        #pragma unroll
        for (int g = 0; g < 4; ++g) acc[g] = __builtin_amdgcn_mfma_f32_16x16x32_f16(ah0, bf[4 + g], acc[g], 0, 0, 0);
        #pragma unroll
        for (int g = 0; g < 4; ++g) acc[g] = __builtin_amdgcn_mfma_f32_16x16x32_f16(ah1, bf[8 + g], acc[g], 0, 0, 0);
        #pragma unroll
        for (int r = 0; r < 4; ++r) {
            float iv = sigm(acc[0][r]), fv = sigm(acc[1][r]);
            float gv = tanhf_(acc[2][r]), ov = sigm(acc[3][r]);
            c1[r] = fv * c1[r] + iv * gv;
            float h1 = ov * tanhf_(c1[r]);
            A0[wA[r] + nbo] = (_Float16)h1;          // single store: L1 reads A0 too
        }
        // stage x_{ph+1} into write half (packed b32); advance 2-deep prefetch
        if (wave < 2) {
            union { _Float16 h[2]; unsigned v; } up;
            up.h[0] = (_Float16)xcur.x; up.h[1] = (_Float16)xcur.y;
            *(unsigned*)&A0[xw + nbo] = up.v;
            xcur = xnxt;
            int tn = ph + 3; if (tn > TT - 1) tn = TT - 1;
            xnxt = *(const float2*)(xbase + (size_t)tn * IN0_);
        }
    };

    auto phaseL1 = [&](int bo) {
        const int nbo = bo ^ 128;
        half8 a0c = *(const half8*)&A0[ar1 + bo];    // h1t lo (from A0!)
        half8 a1c = *(const half8*)&A0[ar2 + bo];    // h1t hi
        half8 a2c = *(const half8*)&A1[ar0 + bo];    // h2 lo
        half8 a3c = *(const half8*)&A1[ar1 + bo];    // h2 hi
        f32x4 acc[4];
        #pragma unroll
        for (int g = 0; g < 4; ++g) { acc[g][0] = bs[g]; acc[g][1] = bs[g]; acc[g][2] = bs[g]; acc[g][3] = bs[g]; }
        #pragma unroll
        for (int g = 0; g < 4; ++g) acc[g] = __builtin_amdgcn_mfma_f32_16x16x32_f16(a0c, bf[g],      acc[g], 0, 0, 0);
        #pragma unroll
        for (int g = 0; g < 4; ++g) acc[g] = __builtin_amdgcn_mfma_f32_16x16x32_f16(a1c, bf[4 + g],  acc[g], 0, 0, 0);
        #pragma unroll
        for (int g = 0; g < 4; ++g) acc[g] = __builtin_amdgcn_mfma_f32_16x16x32_f16(a2c, bf[8 + g],  acc[g], 0, 0, 0);
        #pragma unroll
        for (int g = 0; g < 4; ++g) acc[g] = __builtin_amdgcn_mfma_f32_16x16x32_f16(a3c, bf[12 + g], acc[g], 0, 0, 0);
        #pragma unroll
        for (int r = 0; r < 4; ++r) {
            float iv = sigm(acc[0][r]), fv = sigm(acc[1][r]);
            float gv = tanhf_(acc[2][r]), ov = sigm(acc[3][r]);
            c2[r] = fv * c2[r] + iv * gv;
            float h2 = ov * tanhf_(c2[r]);
            h2r[r] = h2;
            A1[wA[r] + nbo] = (_Float16)h2;
        }
    };

    // ---- main loop: phase ph: L0 computes h1_ph, L1 computes h2_{ph-1} ----
    if (isL0) phaseL0(0, 0);
    BAR();
    #pragma unroll 1
    for (int ph = 1; ph < TT - 1; ph += 2) {
        if (isL0) phaseL0(128, ph); else phaseL1(128);
        BAR();
        if (isL0) phaseL0(0, ph + 1); else phaseL1(0);
        BAR();
    }
    if (isL0) phaseL0(128, TT - 1); else phaseL1(128);   // ph = 511
    BAR();
    if (!isL0) phaseL1(0);                               // ph = 512: final h2

    // ---- FC epilogue (rows 0..7 are real) ----
    if (!isL0) {
        #pragma unroll
        for (int r = 0; r < 4; ++r) fin[(4 * lq + r) * 68 + u] = h2r[r];
    }
    __syncthreads();
    if (tid < BR * 2) {
        int row = tid >> 1, o = tid & 1;
        float a = fcb[o];
        #pragma unroll 1
        for (int u2 = 0; u2 < HH; ++u2)
            a = fmaf(fin[row * 68 + u2], fcw[o * HH + u2], a);
        out[(size_t)(b0 + row) * 2 + o] = a;
    }
}

extern "C" void kernel_launch(void* const* d_in, const int* in_sizes, int n_in,
                              void* d_out, int out_size, void* d_ws, size_t ws_size,
                              hipStream_t stream) {
    const float* x    = (const float*)d_in[0];
    const float* Wih0 = (const float*)d_in[1];
    const float* Whh0 = (const float*)d_in[2];
    const float* bih0 = (const float*)d_in[3];
    const float* bhh0 = (const float*)d_in[4];
    const float* Wih1 = (const float*)d_in[5];
    const float* Whh1 = (const float*)d_in[6];
    const float* bih1 = (const float*)d_in[7];
    const float* bhh1 = (const float*)d_in[8];
    const float* fcw  = (const float*)d_in[9];
    const float* fcb  = (const float*)d_in[10];
    float* out = (float*)d_out;

    dim3 grid(2048 / BR);    // 256 blocks -> 1 per CU: full chip, 2 waves/SIMD
    dim3 block(NT);
    hipLaunchKernelGGL(lstm2_fused, grid, block, 0, stream,
                       x, Wih0, Whh0, bih0, bhh0, Wih1, Whh1, bih1, bhh1, fcw, fcb, out);
}